// Round 6
// baseline (269.508 us; speedup 1.0000x reference)
//
#include <hip/hip_runtime.h>
#include <stdint.h>

constexpr int B = 8, C = 128, H = 64, W = 64, O = 128;
constexpr int HW = H * W;     // 4096
constexpr int NPIX = B * HW;  // 32768
constexpr int NKC = 36;       // k-chunks (9 taps x 4 c-groups of 32)

typedef __bf16 bf16x8 __attribute__((ext_vector_type(8)));
typedef float f32x4 __attribute__((ext_vector_type(4)));
typedef float f32x16 __attribute__((ext_vector_type(16)));
typedef unsigned int ux4 __attribute__((ext_vector_type(4)));

static __device__ __forceinline__ unsigned pack_pair(__bf16 a, __bf16 b) {
    unsigned short ua = __builtin_bit_cast(unsigned short, a);
    unsigned short ub = __builtin_bit_cast(unsigned short, b);
    return (unsigned)ua | ((unsigned)ub << 16);
}

// ---------------- kernel 0a: weight split to bf16 hi/lo ----------------
// wBhi/wBlo[kc=tap*4+ch][o][32 cc] = split(weight[o][ch*32+cc][tap])
__global__ void wsplit_kernel(const float* __restrict__ w,
                              __bf16* __restrict__ wBhi, __bf16* __restrict__ wBlo) {
    int idx = blockIdx.x * 256 + threadIdx.x; // [0, 36*128*32)
    int kk = idx & 31;
    int o = (idx >> 5) & 127;
    int chunk = idx >> 12;
    int tap = chunk >> 2, ch = chunk & 3;
    int c = ch * 32 + kk;
    float v = w[(o * C + c) * 9 + tap];
    __bf16 h = (__bf16)v;
    wBhi[idx] = h;
    wBlo[idx] = (__bf16)(v - (float)h);
}

// ---------------- kernel 0b: offset-weight transpose: owT[c][tap][20] ----------
__global__ void otrans_kernel(const float* __restrict__ ow, float* __restrict__ owT) {
    int idx = blockIdx.x * 256 + threadIdx.x; // [0, 128*9*18)
    if (idx >= C * 9 * 18) return;
    int oc = idx % 18;
    int tap = (idx / 18) % 9;
    int c = idx / (18 * 9);
    owT[(c * 9 + tap) * 20 + oc] = ow[(oc * C + c) * 9 + tap];
}

// ---------------- kernel 1: offset conv partials ----------------
__global__ __launch_bounds__(256) void offconv_part_kernel(
    const float* __restrict__ x, const float* __restrict__ owT,
    float* __restrict__ part) {
    __shared__ float ws[32 * 9 * 20];
    __shared__ float s_red[4][18][64];
    int t = threadIdx.x;
    int bid = blockIdx.x;
    int swz = (bid & 7) * 256 + (bid >> 3);
    int cg = swz & 3;
    int y = (swz >> 2) & 63;
    int b = swz >> 8;
    int px = t & 63, sub = t >> 6;
    const float* src = owT + cg * 5760;
    for (int i = t; i < 5760; i += 256) ws[i] = src[i];
    float m[9];
    int aoff[9];
#pragma unroll
    for (int kh = 0; kh < 3; ++kh)
#pragma unroll
        for (int kw = 0; kw < 3; ++kw) {
            int yy = y + kh - 1, xx = px + kw - 1;
            bool v = (yy >= 0 && yy < H && xx >= 0 && xx < W);
            m[kh * 3 + kw] = v ? 1.f : 0.f;
            aoff[kh * 3 + kw] = min(max(yy, 0), H - 1) * W + min(max(xx, 0), W - 1);
        }
    __syncthreads();
    float acc[18];
#pragma unroll
    for (int o = 0; o < 18; ++o) acc[o] = 0.f;
    const float* xcg = x + (b * C + cg * 32 + sub * 8) * HW;
    for (int c8 = 0; c8 < 8; ++c8) {
        const float* xp = xcg + c8 * HW;
        float xv[9];
#pragma unroll
        for (int tp = 0; tp < 9; ++tp) xv[tp] = m[tp] * xp[aoff[tp]];
        const float* wp = ws + (sub * 8 + c8) * 180;
#pragma unroll
        for (int tp = 0; tp < 9; ++tp) {
            float v = xv[tp];
            float4 w0 = *(const float4*)&wp[tp * 20 + 0];
            float4 w1 = *(const float4*)&wp[tp * 20 + 4];
            float4 w2 = *(const float4*)&wp[tp * 20 + 8];
            float4 w3 = *(const float4*)&wp[tp * 20 + 12];
            float2 w4 = *(const float2*)&wp[tp * 20 + 16];
            acc[0] += v * w0.x;  acc[1] += v * w0.y;  acc[2] += v * w0.z;  acc[3] += v * w0.w;
            acc[4] += v * w1.x;  acc[5] += v * w1.y;  acc[6] += v * w1.z;  acc[7] += v * w1.w;
            acc[8] += v * w2.x;  acc[9] += v * w2.y;  acc[10] += v * w2.z; acc[11] += v * w2.w;
            acc[12] += v * w3.x; acc[13] += v * w3.y; acc[14] += v * w3.z; acc[15] += v * w3.w;
            acc[16] += v * w4.x; acc[17] += v * w4.y;
        }
    }
#pragma unroll
    for (int o = 0; o < 18; ++o) s_red[sub][o][px] = acc[o];
    __syncthreads();
    for (int flat = t; flat < 18 * 64; flat += 256) {
        int oc = flat >> 6, p = flat & 63;
        float v = s_red[0][oc][p] + s_red[1][oc][p] + s_red[2][oc][p] + s_red[3][oc][p];
        part[(cg * B + b) * 18 * HW + oc * HW + y * 64 + p] = v;
    }
}

// ---------------- kernel 1b: reduce partials + bias ----------------
__global__ void offreduce_kernel(const float* __restrict__ part,
                                 const float* __restrict__ ob,
                                 float* __restrict__ offs) {
    int idx = blockIdx.x * 256 + threadIdx.x;
    int oc = (idx >> 12) % 18;
    constexpr int S = B * 18 * HW;
    offs[idx] = ob[oc] + part[idx] + part[S + idx] + part[2 * S + idx] + part[3 * S + idx];
}

// ---------------- shared helper: bilinear setup ----------------
struct BiLin { float w00, w01, w10, w11; int a00, a01, a10, a11; };
static __device__ __forceinline__ BiLin bilin_calc(const float* __restrict__ offs,
                                                   int b, int tap, int y, int px) {
    BiLin r;
    int kh = tap / 3, kw = tap % 3;
    float dy = offs[(b * 18 + 2 * tap) * HW + y * 64 + px];
    float dx = offs[(b * 18 + 2 * tap + 1) * HW + y * 64 + px];
    float ys = (float)(y - 1 + kh) + dy;
    float xs = (float)(px - 1 + kw) + dx;
    float yf = floorf(ys), xf = floorf(xs);
    int iy0 = (int)yf, ix0 = (int)xf;
    int iy1 = iy0 + 1, ix1 = ix0 + 1;
    float wy1 = ys - yf, wy0 = 1.f - wy1;
    float wx1 = xs - xf, wx0 = 1.f - wx1;
    bool vy0 = (iy0 >= 0) & (iy0 < H), vy1 = (iy1 >= 0) & (iy1 < H);
    bool vx0 = (ix0 >= 0) & (ix0 < W), vx1 = (ix1 >= 0) & (ix1 < W);
    int iy0c = min(max(iy0, 0), H - 1), iy1c = min(max(iy1, 0), H - 1);
    int ix0c = min(max(ix0, 0), W - 1), ix1c = min(max(ix1, 0), W - 1);
    r.w00 = (vy0 && vx0) ? wy0 * wx0 : 0.f;
    r.w01 = (vy0 && vx1) ? wy0 * wx1 : 0.f;
    r.w10 = (vy1 && vx0) ? wy1 * wx0 : 0.f;
    r.w11 = (vy1 && vx1) ? wy1 * wx1 : 0.f;
    r.a00 = iy0c * W + ix0c;
    r.a01 = iy0c * W + ix1c;
    r.a10 = iy1c * W + ix0c;
    r.a11 = iy1c * W + ix1c;
    return r;
}

// ---------------- kernel 2a: sampler (decoupled path) ----------------
// grid = 4608 = (b, tap, y); 256 thr = 64 px x 4 c-groups of 32
// writes A_hi/A_lo [kc=tap*4+cq][pixel][32 c] bf16
__global__ __launch_bounds__(256, 2) void sample_kernel(
    const float* __restrict__ x, const float* __restrict__ offs,
    __bf16* __restrict__ Ahi, __bf16* __restrict__ Alo) {
    int t = threadIdx.x;
    int bid = blockIdx.x;
    int swz = (bid & 7) * 576 + (bid >> 3); // 4608 % 8 == 0, bijective
    int b = swz / 576;
    int r = swz % 576;
    int tap = r >> 6;
    int y = r & 63;
    int px = t & 63, cq = t >> 6;

    BiLin s = bilin_calc(offs, b, tap, y, px);
    const float* xc = x + (b * C + cq * 32) * HW;
    int pix = b * HW + y * 64 + px;
    __bf16* dh = Ahi + ((size_t)(tap * 4 + cq) * NPIX + pix) * 32;
    __bf16* dl = Alo + ((size_t)(tap * 4 + cq) * NPIX + pix) * 32;

    unsigned uh[16], ul[16];
#pragma unroll
    for (int c4 = 0; c4 < 8; ++c4) {
        float gv[16];
#pragma unroll
        for (int e = 0; e < 4; ++e) {
            const float* p = xc + (c4 * 4 + e) * HW;
            gv[e * 4 + 0] = p[s.a00];
            gv[e * 4 + 1] = p[s.a01];
            gv[e * 4 + 2] = p[s.a10];
            gv[e * 4 + 3] = p[s.a11];
        }
#pragma unroll
        for (int e2 = 0; e2 < 2; ++e2) {
            float v0 = s.w00 * gv[e2 * 8 + 0] + s.w01 * gv[e2 * 8 + 1] + s.w10 * gv[e2 * 8 + 2] + s.w11 * gv[e2 * 8 + 3];
            float v1 = s.w00 * gv[e2 * 8 + 4] + s.w01 * gv[e2 * 8 + 5] + s.w10 * gv[e2 * 8 + 6] + s.w11 * gv[e2 * 8 + 7];
            __bf16 h0 = (__bf16)v0, h1 = (__bf16)v1;
            __bf16 r0 = (__bf16)(v0 - (float)h0), r1 = (__bf16)(v1 - (float)h1);
            uh[c4 * 2 + e2] = pack_pair(h0, h1);
            ul[c4 * 2 + e2] = pack_pair(r0, r1);
        }
    }
#pragma unroll
    for (int q = 0; q < 4; ++q) {
        *(ux4*)(dh + q * 8) = *(ux4*)&uh[q * 4];
        *(ux4*)(dl + q * 8) = *(ux4*)&ul[q * 4];
    }
}

// ---------------- kernel 2b: MFMA GEMM over materialized A ----------------
// grid = 512 (64-px tiles); 512 thr = 8 waves; wave = 32px x 32o
// A LDS [plane hi/lo][slot=ks*2+lhi][64 px][8 bf16], double-buffered, depth-2 loads
__global__ __launch_bounds__(512, 4) void gemm_kernel(
    const __bf16* __restrict__ Ahi, const __bf16* __restrict__ Alo,
    const __bf16* __restrict__ wBhi, const __bf16* __restrict__ wBlo,
    const float* __restrict__ bias, float* __restrict__ out) {
    __shared__ __bf16 lds[2][4096]; // 2 bufs x 8KB

    int t = threadIdx.x;
    int bid = blockIdx.x;
    int swz = (bid & 7) * 64 + (bid >> 3); // 512 % 8 == 0, bijective
    int px0 = swz * 64;                    // global pixel base (one full b,y row)
    int l31 = t & 31, lhi = (t >> 5) & 1, wv = t >> 6;
    int o = (wv & 3) * 32 + l31;
    int ph = (wv >> 2) * 32;

    // staging map: thread t stages 16B: plane = t>=256 (lo), q = (t>>6)&3, spx = t&63
    // LDS dst byte = t*16 (linear); global src = plane + (kc*NPIX+px0+spx)*32 + q*8
    const __bf16* gsb = (t < 256) ? Ahi : Alo;
    int spx = t & 63, sq = (t >> 6) & 3;
    size_t srow = (size_t)(px0 + spx) * 32 + sq * 8;

    auto gload = [&](int kc) -> ux4 {
        return *(const ux4*)(gsb + (size_t)kc * NPIX * 32 + srow);
    };
    auto swrite = [&](int bi, ux4 v) {
        *(ux4*)&lds[bi][t * 8] = v;
    };
    auto bload = [&](int kc, ux4* d) {
        const __bf16* p = wBhi + ((size_t)kc * 128 + o) * 32 + lhi * 8;
        const __bf16* q = wBlo + ((size_t)kc * 128 + o) * 32 + lhi * 8;
        d[0] = *(const ux4*)(p);
        d[1] = *(const ux4*)(p + 16);
        d[2] = *(const ux4*)(q);
        d[3] = *(const ux4*)(q + 16);
    };

    f32x16 acc;
    {
        float bv = bias[o];
#pragma unroll
        for (int j = 0; j < 16; ++j) acc[j] = bv;
    }

    ux4 gA = gload(0);
    ux4 bcur[4], bnx[4];
    bload(0, bcur);
    swrite(0, gA);
    gA = gload(1);
    __syncthreads();

#pragma unroll 1
    for (int i = 0; i < NKC; ++i) {
        int bi = i & 1;
        if (i < NKC - 1) {
            swrite(bi ^ 1, gA);     // write next chunk (loaded >=1 iter ago)
            bload(i + 1, bnx);      // prefetch B
        }
        if (i < NKC - 2) gA = gload(i + 2); // issue depth-2 A load

        const __bf16* lb = &lds[bi][0];
        int fo = (ph + l31) * 8;
        bf16x8 ah0 = *(const bf16x8*)&lb[(lhi) * 512 + fo];
        bf16x8 ah1 = *(const bf16x8*)&lb[(2 + lhi) * 512 + fo];
        bf16x8 al0 = *(const bf16x8*)&lb[2048 + (lhi) * 512 + fo];
        bf16x8 al1 = *(const bf16x8*)&lb[2048 + (2 + lhi) * 512 + fo];

        bf16x8 b0 = __builtin_bit_cast(bf16x8, bcur[0]);
        bf16x8 b1 = __builtin_bit_cast(bf16x8, bcur[1]);
        bf16x8 b2 = __builtin_bit_cast(bf16x8, bcur[2]);
        bf16x8 b3 = __builtin_bit_cast(bf16x8, bcur[3]);
        acc = __builtin_amdgcn_mfma_f32_32x32x16_bf16(ah0, b0, acc, 0, 0, 0);
        acc = __builtin_amdgcn_mfma_f32_32x32x16_bf16(al0, b0, acc, 0, 0, 0);
        acc = __builtin_amdgcn_mfma_f32_32x32x16_bf16(ah0, b2, acc, 0, 0, 0);
        acc = __builtin_amdgcn_mfma_f32_32x32x16_bf16(ah1, b1, acc, 0, 0, 0);
        acc = __builtin_amdgcn_mfma_f32_32x32x16_bf16(al1, b1, acc, 0, 0, 0);
        acc = __builtin_amdgcn_mfma_f32_32x32x16_bf16(ah1, b3, acc, 0, 0, 0);

        __syncthreads();
        if (i < NKC - 1) {
            bcur[0] = bnx[0]; bcur[1] = bnx[1]; bcur[2] = bnx[2]; bcur[3] = bnx[3];
        }
    }

    // C/D: col = l31 (o), row(px within 32) = (reg&3) + 8*(reg>>2) + 4*lhi
    int b_ = px0 >> 12;
    int rowbase = px0 & 4095;
    float* op = out + ((size_t)b_ * O + o) * HW + rowbase + ph;
#pragma unroll
    for (int gq = 0; gq < 4; ++gq) {
        f32x4 v4;
        v4[0] = acc[gq * 4 + 0];
        v4[1] = acc[gq * 4 + 1];
        v4[2] = acc[gq * 4 + 2];
        v4[3] = acc[gq * 4 + 3];
        *(f32x4*)(op + gq * 8 + lhi * 4) = v4;
    }
}

// ---------------- fallback: round-5 fused kernel (ws too small) ----------------
__global__ __launch_bounds__(256, 4) void deform_fused_kernel(
    const float* __restrict__ x, const float* __restrict__ offs,
    const __bf16* __restrict__ wBhi, const __bf16* __restrict__ wBlo,
    const float* __restrict__ bias, float* __restrict__ out) {
    __shared__ uint2 Ah[2][256], Al[2][256];
    int t = threadIdx.x;
    int bid = blockIdx.x;
    int swz = (bid & 7) * 128 + (bid >> 3);
    int b = swz >> 7;
    int y = (swz >> 1) & 63;
    int half = swz & 1;
    int px0 = half * 32;
    int row0 = y * W;
    const float* xb = x + b * C * HW;
    int l31 = t & 31, lhi = (t >> 5) & 1, wv = t >> 6;
    int o = wv * 32 + l31;
    int spx = t & 31;
    int g = t >> 5;
    BiLin s{};
    float gv[16];
    auto issueA = [&](int chunk) {
        int tap = chunk >> 2, ch = chunk & 3;
        if ((chunk & 3) == 0) s = bilin_calc(offs, b, tap, y, px0 + spx);
        int c0 = ch * 32 + g * 4;
#pragma unroll
        for (int e = 0; e < 4; ++e) {
            const float* p = xb + (c0 + e) * HW;
            gv[e * 4 + 0] = p[s.a00];
            gv[e * 4 + 1] = p[s.a01];
            gv[e * 4 + 2] = p[s.a10];
            gv[e * 4 + 3] = p[s.a11];
        }
    };
    auto finishA = [&](int bi) {
        uint2 qh, ql;
#pragma unroll
        for (int e2 = 0; e2 < 2; ++e2) {
            float v0 = s.w00 * gv[e2 * 8 + 0] + s.w01 * gv[e2 * 8 + 1] + s.w10 * gv[e2 * 8 + 2] + s.w11 * gv[e2 * 8 + 3];
            float v1 = s.w00 * gv[e2 * 8 + 4] + s.w01 * gv[e2 * 8 + 5] + s.w10 * gv[e2 * 8 + 6] + s.w11 * gv[e2 * 8 + 7];
            __bf16 h0 = (__bf16)v0, h1 = (__bf16)v1;
            __bf16 r0 = (__bf16)(v0 - (float)h0), r1 = (__bf16)(v1 - (float)h1);
            unsigned ph = pack_pair(h0, h1);
            unsigned pl = pack_pair(r0, r1);
            if (e2 == 0) { qh.x = ph; ql.x = pl; } else { qh.y = ph; ql.y = pl; }
        }
        int idx = (g >> 1) * 64 + spx * 2 + (g & 1);
        Ah[bi][idx] = qh;
        Al[bi][idx] = ql;
    };
    ux4 bhc[2], blc[2], bhn[2], bln[2];
    auto issueB = [&](int chunk, ux4* bh, ux4* bl) {
        const __bf16* ph = wBhi + chunk * 4096 + o * 32 + lhi * 8;
        const __bf16* pl = wBlo + chunk * 4096 + o * 32 + lhi * 8;
        bh[0] = *(const ux4*)(ph);
        bh[1] = *(const ux4*)(ph + 16);
        bl[0] = *(const ux4*)(pl);
        bl[1] = *(const ux4*)(pl + 16);
    };
    f32x16 acc;
    {
        float bv = bias[o];
#pragma unroll
        for (int j = 0; j < 16; ++j) acc[j] = bv;
    }
    issueB(0, bhc, blc);
    issueA(0);
    finishA(0);
    __syncthreads();
#pragma unroll 1
    for (int i = 0; i < 36; ++i) {
        int bi = i & 1;
        if (i < 35) {
            issueB(i + 1, bhn, bln);
            issueA(i + 1);
        }
#pragma unroll
        for (int sI = 0; sI < 2; ++sI) {
            int u = sI * 2 + lhi;
            bf16x8 ah = __builtin_bit_cast(bf16x8, *(const ux4*)&Ah[bi][u * 64 + l31 * 2]);
            bf16x8 al = __builtin_bit_cast(bf16x8, *(const ux4*)&Al[bi][u * 64 + l31 * 2]);
            bf16x8 bh = __builtin_bit_cast(bf16x8, bhc[sI]);
            bf16x8 bl = __builtin_bit_cast(bf16x8, blc[sI]);
            acc = __builtin_amdgcn_mfma_f32_32x32x16_bf16(ah, bh, acc, 0, 0, 0);
            acc = __builtin_amdgcn_mfma_f32_32x32x16_bf16(al, bh, acc, 0, 0, 0);
            acc = __builtin_amdgcn_mfma_f32_32x32x16_bf16(ah, bl, acc, 0, 0, 0);
        }
        if (i < 35) finishA(bi ^ 1);
        __syncthreads();
        bhc[0] = bhn[0]; bhc[1] = bhn[1];
        blc[0] = bln[0]; blc[1] = bln[1];
    }
    float* op = out + (b * O + o) * HW + row0 + px0;
#pragma unroll
    for (int gq = 0; gq < 4; ++gq) {
        f32x4 v4;
        v4[0] = acc[gq * 4 + 0];
        v4[1] = acc[gq * 4 + 1];
        v4[2] = acc[gq * 4 + 2];
        v4[3] = acc[gq * 4 + 3];
        *(f32x4*)(op + gq * 8 + lhi * 4) = v4;
    }
}

extern "C" void kernel_launch(void* const* d_in, const int* in_sizes, int n_in,
                              void* d_out, int out_size, void* d_ws, size_t ws_size,
                              hipStream_t stream) {
    const float* x        = (const float*)d_in[0];
    const float* offset_w = (const float*)d_in[1];
    const float* offset_b = (const float*)d_in[2];
    const float* weight   = (const float*)d_in[3];
    const float* bias     = (const float*)d_in[4];
    float* out = (float*)d_out;

    float* offs = (float*)d_ws;                    // 589824 f
    float* part = offs + B * 18 * HW;              // 4*589824 f
    float* owT  = part + 4 * B * 18 * HW;          // 23040 f
    __bf16* wBhi = (__bf16*)(owT + 128 * 9 * 20);  // 147456 bf16
    __bf16* wBlo = wBhi + NKC * 128 * 32;
    __bf16* Ahi  = wBlo + NKC * 128 * 32;          // 36*32768*32 bf16 = 75.5 MB
    __bf16* Alo  = Ahi + (size_t)NKC * NPIX * 32;
    size_t need = (size_t)((char*)(Alo + (size_t)NKC * NPIX * 32) - (char*)d_ws);

    wsplit_kernel<<<576, 256, 0, stream>>>(weight, wBhi, wBlo);
    otrans_kernel<<<(C * 9 * 18 + 255) / 256, 256, 0, stream>>>(offset_w, owT);
    offconv_part_kernel<<<2048, 256, 0, stream>>>(x, owT, part);
    offreduce_kernel<<<(B * 18 * HW) / 256, 256, 0, stream>>>(part, offset_b, offs);

    if (ws_size >= need) {
        sample_kernel<<<4608, 256, 0, stream>>>(x, offs, Ahi, Alo);
        gemm_kernel<<<512, 512, 0, stream>>>(Ahi, Alo, wBhi, wBlo, bias, out);
    } else {
        deform_fused_kernel<<<1024, 256, 0, stream>>>(x, offs, wBhi, wBlo, bias, out);
    }
}

// Round 7
// 224.235 us; speedup vs baseline: 1.2019x; 1.2019x over previous
//
#include <hip/hip_runtime.h>
#include <stdint.h>

constexpr int B = 8, C = 128, H = 64, W = 64, O = 128;
constexpr int HW = H * W;     // 4096

typedef __bf16 bf16x8 __attribute__((ext_vector_type(8)));
typedef float f32x4 __attribute__((ext_vector_type(4)));
typedef float f32x16 __attribute__((ext_vector_type(16)));
typedef unsigned int ux4 __attribute__((ext_vector_type(4)));

static __device__ __forceinline__ unsigned pack_pair(__bf16 a, __bf16 b) {
    unsigned short ua = __builtin_bit_cast(unsigned short, a);
    unsigned short ub = __builtin_bit_cast(unsigned short, b);
    return (unsigned)ua | ((unsigned)ub << 16);
}

// ---------------- kernel 0a: weight split to bf16 hi/lo ----------------
// wBhi/wBlo[kc=tap*4+ch][o][32 cc] = split(weight[o][ch*32+cc][tap])
__global__ void wsplit_kernel(const float* __restrict__ w,
                              __bf16* __restrict__ wBhi, __bf16* __restrict__ wBlo) {
    int idx = blockIdx.x * 256 + threadIdx.x; // [0, 36*128*32)
    int kk = idx & 31;
    int o = (idx >> 5) & 127;
    int chunk = idx >> 12;
    int tap = chunk >> 2, ch = chunk & 3;
    int c = ch * 32 + kk;
    float v = w[(o * C + c) * 9 + tap];
    __bf16 h = (__bf16)v;
    wBhi[idx] = h;
    wBlo[idx] = (__bf16)(v - (float)h);
}

// ---------------- kernel 0b: offset-weight transpose: owT[c][tap][20] ----------
__global__ void otrans_kernel(const float* __restrict__ ow, float* __restrict__ owT) {
    int idx = blockIdx.x * 256 + threadIdx.x; // [0, 128*9*18)
    if (idx >= C * 9 * 18) return;
    int oc = idx % 18;
    int tap = (idx / 18) % 9;
    int c = idx / (18 * 9);
    owT[(c * 9 + tap) * 20 + oc] = ow[(oc * C + c) * 9 + tap];
}

// ---------------- kernel 0c: x NCHW -> NHWC (channels-last) ----------------
// grid = 512 (b*64+y); LDS-tiled so both global sides are coalesced
__global__ __launch_bounds__(256) void xtrans_kernel(const float* __restrict__ x,
                                                     float* __restrict__ xt) {
    __shared__ float tile[64][133]; // pad 133: bank=(5*px+c)%32, conflict-free writes
    int t = threadIdx.x;
    int bid = blockIdx.x;
    int b = bid >> 6, y = bid & 63;
    int px = t & 63, cseg = t >> 6;
    const float* xp = x + (size_t)(b * C + cseg * 32) * HW + y * W + px;
#pragma unroll
    for (int i = 0; i < 32; ++i)
        tile[px][cseg * 32 + i] = xp[(size_t)i * HW];
    __syncthreads();
    float* dst = xt + ((size_t)b * HW + y * W) * 128;
#pragma unroll
    for (int j = 0; j < 8; ++j) {
        int flat = j * 1024 + t * 4;
        int ppx = flat >> 7, c = flat & 127;
        f32x4 v;
        v[0] = tile[ppx][c + 0];
        v[1] = tile[ppx][c + 1];
        v[2] = tile[ppx][c + 2];
        v[3] = tile[ppx][c + 3];
        *(f32x4*)&dst[flat] = v;
    }
}

// ---------------- kernel 1: offset conv partials (unchanged) ----------------
__global__ __launch_bounds__(256) void offconv_part_kernel(
    const float* __restrict__ x, const float* __restrict__ owT,
    float* __restrict__ part) {
    __shared__ float ws[32 * 9 * 20];
    __shared__ float s_red[4][18][64];
    int t = threadIdx.x;
    int bid = blockIdx.x;
    int swz = (bid & 7) * 256 + (bid >> 3);
    int cg = swz & 3;
    int y = (swz >> 2) & 63;
    int b = swz >> 8;
    int px = t & 63, sub = t >> 6;
    const float* src = owT + cg * 5760;
    for (int i = t; i < 5760; i += 256) ws[i] = src[i];
    float m[9];
    int aoff[9];
#pragma unroll
    for (int kh = 0; kh < 3; ++kh)
#pragma unroll
        for (int kw = 0; kw < 3; ++kw) {
            int yy = y + kh - 1, xx = px + kw - 1;
            bool v = (yy >= 0 && yy < H && xx >= 0 && xx < W);
            m[kh * 3 + kw] = v ? 1.f : 0.f;
            aoff[kh * 3 + kw] = min(max(yy, 0), H - 1) * W + min(max(xx, 0), W - 1);
        }
    __syncthreads();
    float acc[18];
#pragma unroll
    for (int o = 0; o < 18; ++o) acc[o] = 0.f;
    const float* xcg = x + (b * C + cg * 32 + sub * 8) * HW;
    for (int c8 = 0; c8 < 8; ++c8) {
        const float* xp = xcg + c8 * HW;
        float xv[9];
#pragma unroll
        for (int tp = 0; tp < 9; ++tp) xv[tp] = m[tp] * xp[aoff[tp]];
        const float* wp = ws + (sub * 8 + c8) * 180;
#pragma unroll
        for (int tp = 0; tp < 9; ++tp) {
            float v = xv[tp];
            float4 w0 = *(const float4*)&wp[tp * 20 + 0];
            float4 w1 = *(const float4*)&wp[tp * 20 + 4];
            float4 w2 = *(const float4*)&wp[tp * 20 + 8];
            float4 w3 = *(const float4*)&wp[tp * 20 + 12];
            float2 w4 = *(const float2*)&wp[tp * 20 + 16];
            acc[0] += v * w0.x;  acc[1] += v * w0.y;  acc[2] += v * w0.z;  acc[3] += v * w0.w;
            acc[4] += v * w1.x;  acc[5] += v * w1.y;  acc[6] += v * w1.z;  acc[7] += v * w1.w;
            acc[8] += v * w2.x;  acc[9] += v * w2.y;  acc[10] += v * w2.z; acc[11] += v * w2.w;
            acc[12] += v * w3.x; acc[13] += v * w3.y; acc[14] += v * w3.z; acc[15] += v * w3.w;
            acc[16] += v * w4.x; acc[17] += v * w4.y;
        }
    }
#pragma unroll
    for (int o = 0; o < 18; ++o) s_red[sub][o][px] = acc[o];
    __syncthreads();
    for (int flat = t; flat < 18 * 64; flat += 256) {
        int oc = flat >> 6, p = flat & 63;
        float v = s_red[0][oc][p] + s_red[1][oc][p] + s_red[2][oc][p] + s_red[3][oc][p];
        part[(cg * B + b) * 18 * HW + oc * HW + y * 64 + p] = v;
    }
}

// ---------------- kernel 1b: reduce partials + bias ----------------
__global__ void offreduce_kernel(const float* __restrict__ part,
                                 const float* __restrict__ ob,
                                 float* __restrict__ offs) {
    int idx = blockIdx.x * 256 + threadIdx.x;
    int oc = (idx >> 12) % 18;
    constexpr int S = B * 18 * HW;
    offs[idx] = ob[oc] + part[idx] + part[S + idx] + part[2 * S + idx] + part[3 * S + idx];
}

// ---------------- shared helper: bilinear setup ----------------
struct BiLin { float w00, w01, w10, w11; int a00, a01, a10, a11; };
static __device__ __forceinline__ BiLin bilin_calc(const float* __restrict__ offs,
                                                   int b, int tap, int y, int px) {
    BiLin r;
    int kh = tap / 3, kw = tap % 3;
    float dy = offs[(b * 18 + 2 * tap) * HW + y * 64 + px];
    float dx = offs[(b * 18 + 2 * tap + 1) * HW + y * 64 + px];
    float ys = (float)(y - 1 + kh) + dy;
    float xs = (float)(px - 1 + kw) + dx;
    float yf = floorf(ys), xf = floorf(xs);
    int iy0 = (int)yf, ix0 = (int)xf;
    int iy1 = iy0 + 1, ix1 = ix0 + 1;
    float wy1 = ys - yf, wy0 = 1.f - wy1;
    float wx1 = xs - xf, wx0 = 1.f - wx1;
    bool vy0 = (iy0 >= 0) & (iy0 < H), vy1 = (iy1 >= 0) & (iy1 < H);
    bool vx0 = (ix0 >= 0) & (ix0 < W), vx1 = (ix1 >= 0) & (ix1 < W);
    int iy0c = min(max(iy0, 0), H - 1), iy1c = min(max(iy1, 0), H - 1);
    int ix0c = min(max(ix0, 0), W - 1), ix1c = min(max(ix1, 0), W - 1);
    r.w00 = (vy0 && vx0) ? wy0 * wx0 : 0.f;
    r.w01 = (vy0 && vx1) ? wy0 * wx1 : 0.f;
    r.w10 = (vy1 && vx0) ? wy1 * wx0 : 0.f;
    r.w11 = (vy1 && vx1) ? wy1 * wx1 : 0.f;
    r.a00 = iy0c * W + ix0c;
    r.a01 = iy0c * W + ix1c;
    r.a10 = iy1c * W + ix0c;
    r.a11 = iy1c * W + ix1c;
    return r;
}

// ---------------- kernel 2: fused sample + MFMA GEMM, channels-last gathers ----
// grid = 1024 (b, y, half-row of 32 px); 4 waves, wave = 32px x 32o
// per chunk (32 c): each thread samples 4 c's of one pixel via 4 dense float4 loads
__global__ __launch_bounds__(256, 4) void deform_fused_kernel(
    const float* __restrict__ xt, const float* __restrict__ offs,
    const __bf16* __restrict__ wBhi, const __bf16* __restrict__ wBlo,
    const float* __restrict__ bias, float* __restrict__ out) {
    __shared__ uint2 Ah[2][256], Al[2][256];
    int t = threadIdx.x;
    int bid = blockIdx.x;
    int swz = (bid & 7) * 128 + (bid >> 3); // XCD swizzle, 1024%8==0 bijective
    int b = swz >> 7;
    int y = (swz >> 1) & 63;
    int half = swz & 1;
    int px0 = half * 32;
    int row0 = y * W;
    const float* xb = xt + (size_t)b * HW * 128; // channels-last base
    int l31 = t & 31, lhi = (t >> 5) & 1, wv = t >> 6;
    int o = wv * 32 + l31;
    int spx = t & 31;
    int g = t >> 5; // c-quad 0..7

    BiLin s{};
    f32x4 gq0, gq1, gq2, gq3;
    auto issueA = [&](int chunk) {
        int tap = chunk >> 2, ch = chunk & 3;
        if ((chunk & 3) == 0) s = bilin_calc(offs, b, tap, y, px0 + spx);
        int c0 = ch * 32 + g * 4;
        const float* base = xb + c0;
        gq0 = *(const f32x4*)(base + (size_t)s.a00 * 128);
        gq1 = *(const f32x4*)(base + (size_t)s.a01 * 128);
        gq2 = *(const f32x4*)(base + (size_t)s.a10 * 128);
        gq3 = *(const f32x4*)(base + (size_t)s.a11 * 128);
    };
    auto finishA = [&](int bi) {
        float v[4];
#pragma unroll
        for (int c = 0; c < 4; ++c)
            v[c] = s.w00 * gq0[c] + s.w01 * gq1[c] + s.w10 * gq2[c] + s.w11 * gq3[c];
        __bf16 h0 = (__bf16)v[0], h1 = (__bf16)v[1], h2 = (__bf16)v[2], h3 = (__bf16)v[3];
        uint2 qh, ql;
        qh.x = pack_pair(h0, h1);
        qh.y = pack_pair(h2, h3);
        ql.x = pack_pair((__bf16)(v[0] - (float)h0), (__bf16)(v[1] - (float)h1));
        ql.y = pack_pair((__bf16)(v[2] - (float)h2), (__bf16)(v[3] - (float)h3));
        int idx = (g >> 1) * 64 + spx * 2 + (g & 1);
        Ah[bi][idx] = qh;
        Al[bi][idx] = ql;
    };
    ux4 bhc[2], blc[2], bhn[2], bln[2];
    auto issueB = [&](int chunk, ux4* bh, ux4* bl) {
        const __bf16* ph = wBhi + chunk * 4096 + o * 32 + lhi * 8;
        const __bf16* pl = wBlo + chunk * 4096 + o * 32 + lhi * 8;
        bh[0] = *(const ux4*)(ph);
        bh[1] = *(const ux4*)(ph + 16);
        bl[0] = *(const ux4*)(pl);
        bl[1] = *(const ux4*)(pl + 16);
    };
    f32x16 acc;
    {
        float bv = bias[o];
#pragma unroll
        for (int j = 0; j < 16; ++j) acc[j] = bv;
    }
    issueB(0, bhc, blc);
    issueA(0);
    finishA(0);
    __syncthreads();
#pragma unroll 1
    for (int i = 0; i < 36; ++i) {
        int bi = i & 1;
        if (i < 35) {
            issueB(i + 1, bhn, bln);
            issueA(i + 1);
        }
#pragma unroll
        for (int sI = 0; sI < 2; ++sI) {
            int u = sI * 2 + lhi;
            bf16x8 ah = __builtin_bit_cast(bf16x8, *(const ux4*)&Ah[bi][u * 64 + l31 * 2]);
            bf16x8 al = __builtin_bit_cast(bf16x8, *(const ux4*)&Al[bi][u * 64 + l31 * 2]);
            bf16x8 bh = __builtin_bit_cast(bf16x8, bhc[sI]);
            bf16x8 bl = __builtin_bit_cast(bf16x8, blc[sI]);
            acc = __builtin_amdgcn_mfma_f32_32x32x16_bf16(ah, bh, acc, 0, 0, 0);
            acc = __builtin_amdgcn_mfma_f32_32x32x16_bf16(al, bh, acc, 0, 0, 0);
            acc = __builtin_amdgcn_mfma_f32_32x32x16_bf16(ah, bl, acc, 0, 0, 0);
        }
        if (i < 35) finishA(bi ^ 1);
        __syncthreads();
        bhc[0] = bhn[0]; bhc[1] = bhn[1];
        blc[0] = bln[0]; blc[1] = bln[1];
    }
    float* op = out + ((size_t)b * O + o) * HW + row0 + px0;
#pragma unroll
    for (int gq = 0; gq < 4; ++gq) {
        f32x4 v4;
        v4[0] = acc[gq * 4 + 0];
        v4[1] = acc[gq * 4 + 1];
        v4[2] = acc[gq * 4 + 2];
        v4[3] = acc[gq * 4 + 3];
        *(f32x4*)(op + gq * 8 + lhi * 4) = v4;
    }
}

extern "C" void kernel_launch(void* const* d_in, const int* in_sizes, int n_in,
                              void* d_out, int out_size, void* d_ws, size_t ws_size,
                              hipStream_t stream) {
    const float* x        = (const float*)d_in[0];
    const float* offset_w = (const float*)d_in[1];
    const float* offset_b = (const float*)d_in[2];
    const float* weight   = (const float*)d_in[3];
    const float* bias     = (const float*)d_in[4];
    float* out = (float*)d_out;

    float* offs = (float*)d_ws;                    // 589824 f
    float* part = offs + B * 18 * HW;              // 4*589824 f
    float* owT  = part + 4 * B * 18 * HW;          // 23040 f
    __bf16* wBhi = (__bf16*)(owT + 128 * 9 * 20);  // 147456 bf16
    __bf16* wBlo = wBhi + 36 * 128 * 32;
    float* xt   = (float*)(wBlo + 36 * 128 * 32);  // 8*4096*128 f = 16.8 MB

    wsplit_kernel<<<576, 256, 0, stream>>>(weight, wBhi, wBlo);
    otrans_kernel<<<(C * 9 * 18 + 255) / 256, 256, 0, stream>>>(offset_w, owT);
    xtrans_kernel<<<B * H, 256, 0, stream>>>(x, xt);
    offconv_part_kernel<<<2048, 256, 0, stream>>>(x, owT, part);
    offreduce_kernel<<<(B * 18 * HW) / 256, 256, 0, stream>>>(part, offset_b, offs);
    deform_fused_kernel<<<1024, 256, 0, stream>>>(xt, offs, wBhi, wBlo, bias, out);
}

// Round 8
// 208.057 us; speedup vs baseline: 1.2954x; 1.0778x over previous
//
#include <hip/hip_runtime.h>
#include <stdint.h>

constexpr int B = 8, C = 128, H = 64, W = 64, O = 128;
constexpr int HW = H * W;     // 4096

typedef __bf16 bf16x8 __attribute__((ext_vector_type(8)));
typedef float f32x4 __attribute__((ext_vector_type(4)));
typedef float f32x16 __attribute__((ext_vector_type(16)));
typedef unsigned int ux4 __attribute__((ext_vector_type(4)));

static __device__ __forceinline__ unsigned pack_pair(__bf16 a, __bf16 b) {
    unsigned short ua = __builtin_bit_cast(unsigned short, a);
    unsigned short ub = __builtin_bit_cast(unsigned short, b);
    return (unsigned)ua | ((unsigned)ub << 16);
}

// ---------------- kernel 0a: weight split to bf16 hi/lo, fragment-ready layout --
// dst layout [kc][o>>5][instr=seg>>1][lhi=seg&1][o&31][8] so a wave's B-fragment
// load (lanes = (lhi,l31)) is 1KB contiguous -> 16 line-requests instead of 64.
__global__ void wsplit_kernel(const float* __restrict__ w,
                              __bf16* __restrict__ wBhi, __bf16* __restrict__ wBlo) {
    int idx = blockIdx.x * 256 + threadIdx.x; // [0, 36*128*32)
    int kk = idx & 31;
    int o = (idx >> 5) & 127;
    int chunk = idx >> 12;
    int tap = chunk >> 2, ch = chunk & 3;
    int c = ch * 32 + kk;
    float v = w[(o * C + c) * 9 + tap];
    __bf16 h = (__bf16)v;
    int seg = kk >> 3, e = kk & 7;
    int dst = chunk * 4096 + (o >> 5) * 1024 + (seg >> 1) * 512 + (seg & 1) * 256 + (o & 31) * 8 + e;
    wBhi[dst] = h;
    wBlo[dst] = (__bf16)(v - (float)h);
}

// ---------------- kernel 0b: offset-weight transpose: owT[c][tap][20] ----------
__global__ void otrans_kernel(const float* __restrict__ ow, float* __restrict__ owT) {
    int idx = blockIdx.x * 256 + threadIdx.x; // [0, 128*9*18)
    if (idx >= C * 9 * 18) return;
    int oc = idx % 18;
    int tap = (idx / 18) % 9;
    int c = idx / (18 * 9);
    owT[(c * 9 + tap) * 20 + oc] = ow[(oc * C + c) * 9 + tap];
}

// ---------------- kernel 0c: x NCHW -> NHWC (channels-last) ----------------
__global__ __launch_bounds__(256) void xtrans_kernel(const float* __restrict__ x,
                                                     float* __restrict__ xt) {
    __shared__ float tile[64][133];
    int t = threadIdx.x;
    int bid = blockIdx.x;
    int b = bid >> 6, y = bid & 63;
    int px = t & 63, cseg = t >> 6;
    const float* xp = x + (size_t)(b * C + cseg * 32) * HW + y * W + px;
#pragma unroll
    for (int i = 0; i < 32; ++i)
        tile[px][cseg * 32 + i] = xp[(size_t)i * HW];
    __syncthreads();
    float* dst = xt + ((size_t)b * HW + y * W) * 128;
#pragma unroll
    for (int j = 0; j < 8; ++j) {
        int flat = j * 1024 + t * 4;
        int ppx = flat >> 7, c = flat & 127;
        f32x4 v;
        v[0] = tile[ppx][c + 0];
        v[1] = tile[ppx][c + 1];
        v[2] = tile[ppx][c + 2];
        v[3] = tile[ppx][c + 3];
        *(f32x4*)&dst[flat] = v;
    }
}

// ---------------- kernel 1: offset conv partials (unchanged) ----------------
__global__ __launch_bounds__(256) void offconv_part_kernel(
    const float* __restrict__ x, const float* __restrict__ owT,
    float* __restrict__ part) {
    __shared__ float ws[32 * 9 * 20];
    __shared__ float s_red[4][18][64];
    int t = threadIdx.x;
    int bid = blockIdx.x;
    int swz = (bid & 7) * 256 + (bid >> 3);
    int cg = swz & 3;
    int y = (swz >> 2) & 63;
    int b = swz >> 8;
    int px = t & 63, sub = t >> 6;
    const float* src = owT + cg * 5760;
    for (int i = t; i < 5760; i += 256) ws[i] = src[i];
    float m[9];
    int aoff[9];
#pragma unroll
    for (int kh = 0; kh < 3; ++kh)
#pragma unroll
        for (int kw = 0; kw < 3; ++kw) {
            int yy = y + kh - 1, xx = px + kw - 1;
            bool v = (yy >= 0 && yy < H && xx >= 0 && xx < W);
            m[kh * 3 + kw] = v ? 1.f : 0.f;
            aoff[kh * 3 + kw] = min(max(yy, 0), H - 1) * W + min(max(xx, 0), W - 1);
        }
    __syncthreads();
    float acc[18];
#pragma unroll
    for (int o = 0; o < 18; ++o) acc[o] = 0.f;
    const float* xcg = x + (b * C + cg * 32 + sub * 8) * HW;
    for (int c8 = 0; c8 < 8; ++c8) {
        const float* xp = xcg + c8 * HW;
        float xv[9];
#pragma unroll
        for (int tp = 0; tp < 9; ++tp) xv[tp] = m[tp] * xp[aoff[tp]];
        const float* wp = ws + (sub * 8 + c8) * 180;
#pragma unroll
        for (int tp = 0; tp < 9; ++tp) {
            float v = xv[tp];
            float4 w0 = *(const float4*)&wp[tp * 20 + 0];
            float4 w1 = *(const float4*)&wp[tp * 20 + 4];
            float4 w2 = *(const float4*)&wp[tp * 20 + 8];
            float4 w3 = *(const float4*)&wp[tp * 20 + 12];
            float2 w4 = *(const float2*)&wp[tp * 20 + 16];
            acc[0] += v * w0.x;  acc[1] += v * w0.y;  acc[2] += v * w0.z;  acc[3] += v * w0.w;
            acc[4] += v * w1.x;  acc[5] += v * w1.y;  acc[6] += v * w1.z;  acc[7] += v * w1.w;
            acc[8] += v * w2.x;  acc[9] += v * w2.y;  acc[10] += v * w2.z; acc[11] += v * w2.w;
            acc[12] += v * w3.x; acc[13] += v * w3.y; acc[14] += v * w3.z; acc[15] += v * w3.w;
            acc[16] += v * w4.x; acc[17] += v * w4.y;
        }
    }
#pragma unroll
    for (int o = 0; o < 18; ++o) s_red[sub][o][px] = acc[o];
    __syncthreads();
    for (int flat = t; flat < 18 * 64; flat += 256) {
        int oc = flat >> 6, p = flat & 63;
        float v = s_red[0][oc][p] + s_red[1][oc][p] + s_red[2][oc][p] + s_red[3][oc][p];
        part[(cg * B + b) * 18 * HW + oc * HW + y * 64 + p] = v;
    }
}

// ---------------- kernel 1b: reduce partials + bias ----------------
__global__ void offreduce_kernel(const float* __restrict__ part,
                                 const float* __restrict__ ob,
                                 float* __restrict__ offs) {
    int idx = blockIdx.x * 256 + threadIdx.x;
    int oc = (idx >> 12) % 18;
    constexpr int S = B * 18 * HW;
    offs[idx] = ob[oc] + part[idx] + part[S + idx] + part[2 * S + idx] + part[3 * S + idx];
}

// ---------------- shared helper: bilinear setup ----------------
struct BiLin { float w00, w01, w10, w11; int a00, a01, a10, a11; };
static __device__ __forceinline__ BiLin bilin_calc(const float* __restrict__ offs,
                                                   int b, int tap, int y, int px) {
    BiLin r;
    int kh = tap / 3, kw = tap % 3;
    float dy = offs[(b * 18 + 2 * tap) * HW + y * 64 + px];
    float dx = offs[(b * 18 + 2 * tap + 1) * HW + y * 64 + px];
    float ys = (float)(y - 1 + kh) + dy;
    float xs = (float)(px - 1 + kw) + dx;
    float yf = floorf(ys), xf = floorf(xs);
    int iy0 = (int)yf, ix0 = (int)xf;
    int iy1 = iy0 + 1, ix1 = ix0 + 1;
    float wy1 = ys - yf, wy0 = 1.f - wy1;
    float wx1 = xs - xf, wx0 = 1.f - wx1;
    bool vy0 = (iy0 >= 0) & (iy0 < H), vy1 = (iy1 >= 0) & (iy1 < H);
    bool vx0 = (ix0 >= 0) & (ix0 < W), vx1 = (ix1 >= 0) & (ix1 < W);
    int iy0c = min(max(iy0, 0), H - 1), iy1c = min(max(iy1, 0), H - 1);
    int ix0c = min(max(ix0, 0), W - 1), ix1c = min(max(ix1, 0), W - 1);
    r.w00 = (vy0 && vx0) ? wy0 * wx0 : 0.f;
    r.w01 = (vy0 && vx1) ? wy0 * wx1 : 0.f;
    r.w10 = (vy1 && vx0) ? wy1 * wx0 : 0.f;
    r.w11 = (vy1 && vx1) ? wy1 * wx1 : 0.f;
    r.a00 = iy0c * W + ix0c;
    r.a01 = iy0c * W + ix1c;
    r.a10 = iy1c * W + ix0c;
    r.a11 = iy1c * W + ix1c;
    return r;
}

// ---------------- kernel 2: fused sample + MFMA GEMM ----------------
// grid = 1024 (b, y, half-row of 32 px); 4 waves, wave = 32px x 32o
// A: dense NHWC float4 gathers; B: fragment-ready coalesced 1KB/wave loads
__global__ __launch_bounds__(256, 4) void deform_fused_kernel(
    const float* __restrict__ xt, const float* __restrict__ offs,
    const __bf16* __restrict__ wBhi, const __bf16* __restrict__ wBlo,
    const float* __restrict__ bias, float* __restrict__ out) {
    __shared__ uint2 Ah[2][256], Al[2][256];
    int t = threadIdx.x;
    int bid = blockIdx.x;
    int swz = (bid & 7) * 128 + (bid >> 3); // XCD swizzle, 1024%8==0 bijective
    int b = swz >> 7;
    int y = (swz >> 1) & 63;
    int half = swz & 1;
    int px0 = half * 32;
    int row0 = y * W;
    const float* xb = xt + (size_t)b * HW * 128;
    int l31 = t & 31, lhi = (t >> 5) & 1, wv = t >> 6;
    int o = wv * 32 + l31;
    int spx = t & 31;
    int g = t >> 5; // c-quad 0..7

    BiLin s{};
    f32x4 gq0, gq1, gq2, gq3;
    auto issueA = [&](int chunk) {
        int tap = chunk >> 2, ch = chunk & 3;
        if ((chunk & 3) == 0) s = bilin_calc(offs, b, tap, y, px0 + spx);
        int c0 = ch * 32 + g * 4;
        const float* base = xb + c0;
        gq0 = *(const f32x4*)(base + (size_t)s.a00 * 128);
        gq1 = *(const f32x4*)(base + (size_t)s.a01 * 128);
        gq2 = *(const f32x4*)(base + (size_t)s.a10 * 128);
        gq3 = *(const f32x4*)(base + (size_t)s.a11 * 128);
    };
    auto finishA = [&](int bi) {
        float v[4];
#pragma unroll
        for (int c = 0; c < 4; ++c)
            v[c] = s.w00 * gq0[c] + s.w01 * gq1[c] + s.w10 * gq2[c] + s.w11 * gq3[c];
        __bf16 h0 = (__bf16)v[0], h1 = (__bf16)v[1], h2 = (__bf16)v[2], h3 = (__bf16)v[3];
        uint2 qh, ql;
        qh.x = pack_pair(h0, h1);
        qh.y = pack_pair(h2, h3);
        ql.x = pack_pair((__bf16)(v[0] - (float)h0), (__bf16)(v[1] - (float)h1));
        ql.y = pack_pair((__bf16)(v[2] - (float)h2), (__bf16)(v[3] - (float)h3));
        int idx = (g >> 1) * 64 + spx * 2 + (g & 1);
        Ah[bi][idx] = qh;
        Al[bi][idx] = ql;
    };
    ux4 bhc[2], blc[2], bhn[2], bln[2];
    // B fragment loads: lanes (lhi,l31) read contiguous 1KB per instruction
    auto issueB = [&](int chunk, ux4* bh, ux4* bl) {
        size_t fo = (size_t)chunk * 4096 + wv * 1024 + lhi * 256 + l31 * 8;
        const __bf16* ph = wBhi + fo;
        const __bf16* pl = wBlo + fo;
        bh[0] = *(const ux4*)(ph);        // c[lhi*8 .. +8)
        bh[1] = *(const ux4*)(ph + 512);  // c[16 + lhi*8 .. +8)
        bl[0] = *(const ux4*)(pl);
        bl[1] = *(const ux4*)(pl + 512);
    };
    f32x16 acc;
    {
        float bv = bias[o];
#pragma unroll
        for (int j = 0; j < 16; ++j) acc[j] = bv;
    }
    issueB(0, bhc, blc);
    issueA(0);
    finishA(0);
    __syncthreads();
#pragma unroll 1
    for (int i = 0; i < 36; ++i) {
        int bi = i & 1;
        if (i < 35) {
            issueB(i + 1, bhn, bln);
            issueA(i + 1);
        }
#pragma unroll
        for (int sI = 0; sI < 2; ++sI) {
            int u = sI * 2 + lhi;
            bf16x8 ah = __builtin_bit_cast(bf16x8, *(const ux4*)&Ah[bi][u * 64 + l31 * 2]);
            bf16x8 al = __builtin_bit_cast(bf16x8, *(const ux4*)&Al[bi][u * 64 + l31 * 2]);
            bf16x8 bh = __builtin_bit_cast(bf16x8, bhc[sI]);
            bf16x8 bl = __builtin_bit_cast(bf16x8, blc[sI]);
            acc = __builtin_amdgcn_mfma_f32_32x32x16_bf16(ah, bh, acc, 0, 0, 0);
            acc = __builtin_amdgcn_mfma_f32_32x32x16_bf16(al, bh, acc, 0, 0, 0);
            acc = __builtin_amdgcn_mfma_f32_32x32x16_bf16(ah, bl, acc, 0, 0, 0);
        }
        if (i < 35) finishA(bi ^ 1);
        __syncthreads();
        bhc[0] = bhn[0]; bhc[1] = bhn[1];
        blc[0] = bln[0]; blc[1] = bln[1];
    }
    float* op = out + ((size_t)b * O + o) * HW + row0 + px0;
#pragma unroll
    for (int gq = 0; gq < 4; ++gq) {
        f32x4 v4;
        v4[0] = acc[gq * 4 + 0];
        v4[1] = acc[gq * 4 + 1];
        v4[2] = acc[gq * 4 + 2];
        v4[3] = acc[gq * 4 + 3];
        *(f32x4*)(op + gq * 8 + lhi * 4) = v4;
    }
}

extern "C" void kernel_launch(void* const* d_in, const int* in_sizes, int n_in,
                              void* d_out, int out_size, void* d_ws, size_t ws_size,
                              hipStream_t stream) {
    const float* x        = (const float*)d_in[0];
    const float* offset_w = (const float*)d_in[1];
    const float* offset_b = (const float*)d_in[2];
    const float* weight   = (const float*)d_in[3];
    const float* bias     = (const float*)d_in[4];
    float* out = (float*)d_out;

    float* offs = (float*)d_ws;                    // 589824 f
    float* part = offs + B * 18 * HW;              // 4*589824 f
    float* owT  = part + 4 * B * 18 * HW;          // 23040 f
    __bf16* wBhi = (__bf16*)(owT + 128 * 9 * 20);  // 147456 bf16
    __bf16* wBlo = wBhi + 36 * 128 * 32;
    float* xt   = (float*)(wBlo + 36 * 128 * 32);  // 8*4096*128 f = 16.8 MB

    wsplit_kernel<<<576, 256, 0, stream>>>(weight, wBhi, wBlo);
    otrans_kernel<<<(C * 9 * 18 + 255) / 256, 256, 0, stream>>>(offset_w, owT);
    xtrans_kernel<<<B * H, 256, 0, stream>>>(x, xt);
    offconv_part_kernel<<<2048, 256, 0, stream>>>(x, owT, part);
    offreduce_kernel<<<(B * 18 * HW) / 256, 256, 0, stream>>>(part, offset_b, offs);
    deform_fused_kernel<<<1024, 256, 0, stream>>>(xt, offs, wBhi, wBlo, bias, out);
}

// Round 9
// 174.711 us; speedup vs baseline: 1.5426x; 1.1909x over previous
//
#include <hip/hip_runtime.h>
#include <stdint.h>

constexpr int B = 8, C = 128, H = 64, W = 64, O = 128;
constexpr int HW = H * W;     // 4096

typedef __bf16 bf16x8 __attribute__((ext_vector_type(8)));
typedef float f32x4 __attribute__((ext_vector_type(4)));
typedef float f32x16 __attribute__((ext_vector_type(16)));
typedef unsigned int ux4 __attribute__((ext_vector_type(4)));

static __device__ __forceinline__ unsigned pack_pair(__bf16 a, __bf16 b) {
    unsigned short ua = __builtin_bit_cast(unsigned short, a);
    unsigned short ub = __builtin_bit_cast(unsigned short, b);
    return (unsigned)ua | ((unsigned)ub << 16);
}

// ---------------- kernel 0a: weight split to bf16 hi/lo, fragment-ready layout --
// dst [kc][o>>5][seg>>1][seg&1][o&31][8]: a wave's B-fragment load is 1KB contiguous
__global__ void wsplit_kernel(const float* __restrict__ w,
                              __bf16* __restrict__ wBhi, __bf16* __restrict__ wBlo) {
    int idx = blockIdx.x * 256 + threadIdx.x; // [0, 36*128*32)
    int kk = idx & 31;
    int o = (idx >> 5) & 127;
    int chunk = idx >> 12;
    int tap = chunk >> 2, ch = chunk & 3;
    int c = ch * 32 + kk;
    float v = w[(o * C + c) * 9 + tap];
    __bf16 h = (__bf16)v;
    int seg = kk >> 3, e = kk & 7;
    int dst = chunk * 4096 + (o >> 5) * 1024 + (seg >> 1) * 512 + (seg & 1) * 256 + (o & 31) * 8 + e;
    wBhi[dst] = h;
    wBlo[dst] = (__bf16)(v - (float)h);
}

// ---------------- kernel 0b: offset-weight transpose: owT[c][tap][20] ----------
__global__ void otrans_kernel(const float* __restrict__ ow, float* __restrict__ owT) {
    int idx = blockIdx.x * 256 + threadIdx.x; // [0, 128*9*18)
    if (idx >= C * 9 * 18) return;
    int oc = idx % 18;
    int tap = (idx / 18) % 9;
    int c = idx / (18 * 9);
    owT[(c * 9 + tap) * 20 + oc] = ow[(oc * C + c) * 9 + tap];
}

// ---------------- kernel 0c: x NCHW -> NHWC (channels-last) ----------------
__global__ __launch_bounds__(256) void xtrans_kernel(const float* __restrict__ x,
                                                     float* __restrict__ xt) {
    __shared__ float tile[64][133];
    int t = threadIdx.x;
    int bid = blockIdx.x;
    int b = bid >> 6, y = bid & 63;
    int px = t & 63, cseg = t >> 6;
    const float* xp = x + (size_t)(b * C + cseg * 32) * HW + y * W + px;
#pragma unroll
    for (int i = 0; i < 32; ++i)
        tile[px][cseg * 32 + i] = xp[(size_t)i * HW];
    __syncthreads();
    float* dst = xt + ((size_t)b * HW + y * W) * 128;
#pragma unroll
    for (int j = 0; j < 8; ++j) {
        int flat = j * 1024 + t * 4;
        int ppx = flat >> 7, c = flat & 127;
        f32x4 v;
        v[0] = tile[ppx][c + 0];
        v[1] = tile[ppx][c + 1];
        v[2] = tile[ppx][c + 2];
        v[3] = tile[ppx][c + 3];
        *(f32x4*)&dst[flat] = v;
    }
}

// ---------------- kernel 1: offset conv partials (unchanged) ----------------
__global__ __launch_bounds__(256) void offconv_part_kernel(
    const float* __restrict__ x, const float* __restrict__ owT,
    float* __restrict__ part) {
    __shared__ float ws[32 * 9 * 20];
    __shared__ float s_red[4][18][64];
    int t = threadIdx.x;
    int bid = blockIdx.x;
    int swz = (bid & 7) * 256 + (bid >> 3);
    int cg = swz & 3;
    int y = (swz >> 2) & 63;
    int b = swz >> 8;
    int px = t & 63, sub = t >> 6;
    const float* src = owT + cg * 5760;
    for (int i = t; i < 5760; i += 256) ws[i] = src[i];
    float m[9];
    int aoff[9];
#pragma unroll
    for (int kh = 0; kh < 3; ++kh)
#pragma unroll
        for (int kw = 0; kw < 3; ++kw) {
            int yy = y + kh - 1, xx = px + kw - 1;
            bool v = (yy >= 0 && yy < H && xx >= 0 && xx < W);
            m[kh * 3 + kw] = v ? 1.f : 0.f;
            aoff[kh * 3 + kw] = min(max(yy, 0), H - 1) * W + min(max(xx, 0), W - 1);
        }
    __syncthreads();
    float acc[18];
#pragma unroll
    for (int o = 0; o < 18; ++o) acc[o] = 0.f;
    const float* xcg = x + (b * C + cg * 32 + sub * 8) * HW;
    for (int c8 = 0; c8 < 8; ++c8) {
        const float* xp = xcg + c8 * HW;
        float xv[9];
#pragma unroll
        for (int tp = 0; tp < 9; ++tp) xv[tp] = m[tp] * xp[aoff[tp]];
        const float* wp = ws + (sub * 8 + c8) * 180;
#pragma unroll
        for (int tp = 0; tp < 9; ++tp) {
            float v = xv[tp];
            float4 w0 = *(const float4*)&wp[tp * 20 + 0];
            float4 w1 = *(const float4*)&wp[tp * 20 + 4];
            float4 w2 = *(const float4*)&wp[tp * 20 + 8];
            float4 w3 = *(const float4*)&wp[tp * 20 + 12];
            float2 w4 = *(const float2*)&wp[tp * 20 + 16];
            acc[0] += v * w0.x;  acc[1] += v * w0.y;  acc[2] += v * w0.z;  acc[3] += v * w0.w;
            acc[4] += v * w1.x;  acc[5] += v * w1.y;  acc[6] += v * w1.z;  acc[7] += v * w1.w;
            acc[8] += v * w2.x;  acc[9] += v * w2.y;  acc[10] += v * w2.z; acc[11] += v * w2.w;
            acc[12] += v * w3.x; acc[13] += v * w3.y; acc[14] += v * w3.z; acc[15] += v * w3.w;
            acc[16] += v * w4.x; acc[17] += v * w4.y;
        }
    }
#pragma unroll
    for (int o = 0; o < 18; ++o) s_red[sub][o][px] = acc[o];
    __syncthreads();
    for (int flat = t; flat < 18 * 64; flat += 256) {
        int oc = flat >> 6, p = flat & 63;
        float v = s_red[0][oc][p] + s_red[1][oc][p] + s_red[2][oc][p] + s_red[3][oc][p];
        part[(cg * B + b) * 18 * HW + oc * HW + y * 64 + p] = v;
    }
}

// ---------------- kernel 1b: reduce partials + bias ----------------
__global__ void offreduce_kernel(const float* __restrict__ part,
                                 const float* __restrict__ ob,
                                 float* __restrict__ offs) {
    int idx = blockIdx.x * 256 + threadIdx.x;
    int oc = (idx >> 12) % 18;
    constexpr int S = B * 18 * HW;
    offs[idx] = ob[oc] + part[idx] + part[S + idx] + part[2 * S + idx] + part[3 * S + idx];
}

// ---------------- shared helper: bilinear setup ----------------
struct BiLin { float w00, w01, w10, w11; int a00, a01, a10, a11; };
static __device__ __forceinline__ BiLin bilin_calc(const float* __restrict__ offs,
                                                   int b, int tap, int y, int px) {
    BiLin r;
    int kh = tap / 3, kw = tap % 3;
    float dy = offs[(b * 18 + 2 * tap) * HW + y * 64 + px];
    float dx = offs[(b * 18 + 2 * tap + 1) * HW + y * 64 + px];
    float ys = (float)(y - 1 + kh) + dy;
    float xs = (float)(px - 1 + kw) + dx;
    float yf = floorf(ys), xf = floorf(xs);
    int iy0 = (int)yf, ix0 = (int)xf;
    int iy1 = iy0 + 1, ix1 = ix0 + 1;
    float wy1 = ys - yf, wy0 = 1.f - wy1;
    float wx1 = xs - xf, wx0 = 1.f - wx1;
    bool vy0 = (iy0 >= 0) & (iy0 < H), vy1 = (iy1 >= 0) & (iy1 < H);
    bool vx0 = (ix0 >= 0) & (ix0 < W), vx1 = (ix1 >= 0) & (ix1 < W);
    int iy0c = min(max(iy0, 0), H - 1), iy1c = min(max(iy1, 0), H - 1);
    int ix0c = min(max(ix0, 0), W - 1), ix1c = min(max(ix1, 0), W - 1);
    r.w00 = (vy0 && vx0) ? wy0 * wx0 : 0.f;
    r.w01 = (vy0 && vx1) ? wy0 * wx1 : 0.f;
    r.w10 = (vy1 && vx0) ? wy1 * wx0 : 0.f;
    r.w11 = (vy1 && vx1) ? wy1 * wx1 : 0.f;
    r.a00 = iy0c * W + ix0c;
    r.a01 = iy0c * W + ix1c;
    r.a10 = iy1c * W + ix0c;
    r.a11 = iy1c * W + ix1c;
    return r;
}

// ---------------- kernel 2: fused sample + MFMA GEMM, 64px tile, 8 waves ------
// grid = 512 (b, y = full row of 64 px); 512 thr
// consumer: wave wv -> (wm = wv&1 px-half, wn = wv>>1 o-block); lane (l31, lhi)
// producer: wave wv -> px quarter (wv&3), c-half (wv>>2); lane -> (px = q*16+(lane>>2), quad = lane&3)
//   gather: 4 quads of one pixel-corner = contiguous 64B = one line-request
// B: reg-staged to LDS once per block (no per-wave duplicate fetches)
__global__ __launch_bounds__(512, 4) void deform_fused_kernel(
    const float* __restrict__ xt, const float* __restrict__ offs,
    const __bf16* __restrict__ wBhi, const __bf16* __restrict__ wBlo,
    const float* __restrict__ bias, float* __restrict__ out) {
    __shared__ uint2 AhL[2][512], AlL[2][512];        // 8KB + 8KB
    __shared__ __bf16 BldsH[2][4096], BldsL[2][4096]; // 16KB + 16KB

    int t = threadIdx.x;
    int bid = blockIdx.x;
    int swz = (bid & 7) * 64 + (bid >> 3); // XCD swizzle, 512%8==0 bijective
    int b = swz >> 6, y = swz & 63;
    int row0 = y * W;
    const float* xb = xt + (size_t)b * HW * 128;

    int lane = t & 63;
    int wv = t >> 6;
    int l31 = t & 31, lhi = (t >> 5) & 1;
    int wm = wv & 1, wn = wv >> 1;
    int o = wn * 32 + l31;

    // producer mapping
    int ppx = (wv & 3) * 16 + (lane >> 2);
    int q = lane & 3;
    int chalf = wv >> 2;
    int g = chalf * 4 + q;

    BiLin s{};
    f32x4 greg[4];
    auto issueG = [&](int chunk) {
        int tap = chunk >> 2, ch = chunk & 3;
        if ((chunk & 3) == 0) s = bilin_calc(offs, b, tap, y, ppx);
        const float* base = xb + ch * 32 + chalf * 16 + q * 4;
        greg[0] = *(const f32x4*)(base + (size_t)s.a00 * 128);
        greg[1] = *(const f32x4*)(base + (size_t)s.a01 * 128);
        greg[2] = *(const f32x4*)(base + (size_t)s.a10 * 128);
        greg[3] = *(const f32x4*)(base + (size_t)s.a11 * 128);
    };
    auto finishA = [&](int bufi) {
        float v0 = s.w00 * greg[0][0] + s.w01 * greg[1][0] + s.w10 * greg[2][0] + s.w11 * greg[3][0];
        float v1 = s.w00 * greg[0][1] + s.w01 * greg[1][1] + s.w10 * greg[2][1] + s.w11 * greg[3][1];
        float v2 = s.w00 * greg[0][2] + s.w01 * greg[1][2] + s.w10 * greg[2][2] + s.w11 * greg[3][2];
        float v3 = s.w00 * greg[0][3] + s.w01 * greg[1][3] + s.w10 * greg[2][3] + s.w11 * greg[3][3];
        __bf16 h0 = (__bf16)v0, h1 = (__bf16)v1, h2 = (__bf16)v2, h3 = (__bf16)v3;
        uint2 qh, ql;
        qh.x = pack_pair(h0, h1);
        qh.y = pack_pair(h2, h3);
        ql.x = pack_pair((__bf16)(v0 - (float)h0), (__bf16)(v1 - (float)h1));
        ql.y = pack_pair((__bf16)(v2 - (float)h2), (__bf16)(v3 - (float)h3));
        int idx = (g >> 1) * 128 + ppx * 2 + (g & 1);
        AhL[bufi][idx] = qh;
        AlL[bufi][idx] = ql;
    };

    ux4 bregH, bregL;
    auto issueBload = [&](int chunk) {
        const __bf16* ph = wBhi + (size_t)chunk * 4096 + wv * 512 + lane * 8;
        const __bf16* pl = wBlo + (size_t)chunk * 4096 + wv * 512 + lane * 8;
        bregH = *(const ux4*)ph;
        bregL = *(const ux4*)pl;
    };
    auto writeB = [&](int bufi) {
        *(ux4*)&BldsH[bufi][wv * 512 + lane * 8] = bregH;
        *(ux4*)&BldsL[bufi][wv * 512 + lane * 8] = bregL;
    };

    f32x16 acc;
    {
        float bv = bias[o];
#pragma unroll
        for (int j = 0; j < 16; ++j) acc[j] = bv;
    }

    auto domfma = [&](int bufi) {
#pragma unroll
        for (int sI = 0; sI < 2; ++sI) {
            int u = sI * 2 + lhi;
            bf16x8 ah = __builtin_bit_cast(bf16x8, *(const ux4*)&AhL[bufi][u * 128 + (wm * 32 + l31) * 2]);
            bf16x8 al = __builtin_bit_cast(bf16x8, *(const ux4*)&AlL[bufi][u * 128 + (wm * 32 + l31) * 2]);
            bf16x8 bh = __builtin_bit_cast(bf16x8, *(const ux4*)&BldsH[bufi][wn * 1024 + sI * 512 + lhi * 256 + l31 * 8]);
            bf16x8 bl = __builtin_bit_cast(bf16x8, *(const ux4*)&BldsL[bufi][wn * 1024 + sI * 512 + lhi * 256 + l31 * 8]);
            acc = __builtin_amdgcn_mfma_f32_32x32x16_bf16(ah, bh, acc, 0, 0, 0);
            acc = __builtin_amdgcn_mfma_f32_32x32x16_bf16(al, bh, acc, 0, 0, 0);
            acc = __builtin_amdgcn_mfma_f32_32x32x16_bf16(ah, bl, acc, 0, 0, 0);
        }
    };

    // prologue: stage chunk 0, issue gathers for chunk 1
    issueG(0);
    issueBload(0);
    finishA(0);
    writeB(0);
    issueG(1);
    __syncthreads();

#pragma unroll 1
    for (int i = 0; i < 36; ++i) {
        int bi = i & 1;
        if (i < 35) issueBload(i + 1);      // early issue (T14 split)
        domfma(bi);
        if (i < 35) {
            finishA(bi ^ 1);                // greg holds chunk i+1
            writeB(bi ^ 1);
        }
        __syncthreads();
        if (i < 34) issueG(i + 2);          // full-iteration latency cover
    }

    // C/D: col = l31 (o), row(px within 32) = (reg&3) + 8*(reg>>2) + 4*lhi
    float* op = out + ((size_t)b * O + o) * HW + row0 + wm * 32;
#pragma unroll
    for (int gq = 0; gq < 4; ++gq) {
        f32x4 v4;
        v4[0] = acc[gq * 4 + 0];
        v4[1] = acc[gq * 4 + 1];
        v4[2] = acc[gq * 4 + 2];
        v4[3] = acc[gq * 4 + 3];
        *(f32x4*)(op + gq * 8 + lhi * 4) = v4;
    }
}

extern "C" void kernel_launch(void* const* d_in, const int* in_sizes, int n_in,
                              void* d_out, int out_size, void* d_ws, size_t ws_size,
                              hipStream_t stream) {
    const float* x        = (const float*)d_in[0];
    const float* offset_w = (const float*)d_in[1];
    const float* offset_b = (const float*)d_in[2];
    const float* weight   = (const float*)d_in[3];
    const float* bias     = (const float*)d_in[4];
    float* out = (float*)d_out;

    float* offs = (float*)d_ws;                    // 589824 f
    float* part = offs + B * 18 * HW;              // 4*589824 f
    float* owT  = part + 4 * B * 18 * HW;          // 23040 f
    __bf16* wBhi = (__bf16*)(owT + 128 * 9 * 20);  // 147456 bf16
    __bf16* wBlo = wBhi + 36 * 128 * 32;
    float* xt   = (float*)(wBlo + 36 * 128 * 32);  // 8*4096*128 f = 16.8 MB

    wsplit_kernel<<<576, 256, 0, stream>>>(weight, wBhi, wBlo);
    otrans_kernel<<<(C * 9 * 18 + 255) / 256, 256, 0, stream>>>(offset_w, owT);
    xtrans_kernel<<<B * H, 256, 0, stream>>>(x, xt);
    offconv_part_kernel<<<2048, 256, 0, stream>>>(x, owT, part);
    offreduce_kernel<<<(B * 18 * HW) / 256, 256, 0, stream>>>(part, offset_b, offs);
    deform_fused_kernel<<<512, 512, 0, stream>>>(xt, offs, wBhi, wBlo, bias, out);
}